// Round 1
// baseline (610.757 us; speedup 1.0000x reference)
//
#include <hip/hip_runtime.h>

typedef unsigned short U16;
typedef unsigned int U32;
typedef __bf16 bf16;
typedef bf16 bf16x8 __attribute__((ext_vector_type(8)));
typedef U16  u16x8  __attribute__((ext_vector_type(8)));
typedef float f32x4 __attribute__((ext_vector_type(4)));

// Exact 3-limb bf16 chop split: a == a1 + a2 + a3 (fp32 24-bit significand
// = 3 x 8-bit bf16 limbs; bf16 exponent range == fp32 so no subnormal loss).
__device__ __forceinline__ void split3(float a, U16& o1, U16& o2, U16& o3) {
    U32 ua = __float_as_uint(a);
    float a1 = __uint_as_float(ua & 0xFFFF0000u);
    float r1 = a - a1;
    U32 u2 = __float_as_uint(r1);
    float a2 = __uint_as_float(u2 & 0xFFFF0000u);
    float r2 = r1 - a2;                     // exact in bf16 (<=8 sig bits left)
    o1 = (U16)(ua >> 16);
    o2 = (U16)(u2 >> 16);
    o3 = (U16)(__float_as_uint(r2) >> 16);
}

__device__ __forceinline__ void split3x8(const float v[8], bf16x8& A1, bf16x8& A2, bf16x8& A3) {
    u16x8 e1, e2, e3;
    #pragma unroll
    for (int j = 0; j < 8; ++j) { U16 a, b, c; split3(v[j], a, b, c); e1[j] = a; e2[j] = b; e3[j] = c; }
    A1 = __builtin_bit_cast(bf16x8, e1);
    A2 = __builtin_bit_cast(bf16x8, e2);
    A3 = __builtin_bit_cast(bf16x8, e3);
}

// ---------------- prep: split w1/w2 into bf16 limb planes in d_ws ----------
// w1L: [3][128 n][128 k] bf16 (k 112..127 zero)  = 98304 B at ws+0
// w2L: [3][32 n][128 k]  bf16                    = 24576 B at ws+98304
__global__ __launch_bounds__(256)
void prep_kernel(const float* __restrict__ w1g, const float* __restrict__ w2g,
                 U16* __restrict__ w1L, U16* __restrict__ w2L)
{
    int tid = blockIdx.x * 256 + threadIdx.x;
    if (tid < 2048) {                       // 128 rows x 16 slots of 8 k
        int n = tid >> 4, k0 = (tid & 15) << 3;
        float v[8];
        #pragma unroll
        for (int j = 0; j < 8; ++j) { int k = k0 + j; v[j] = (k < 112) ? w1g[n * 112 + k] : 0.0f; }
        bf16x8 L1, L2, L3; split3x8(v, L1, L2, L3);
        *(bf16x8*)(w1L + 0 * 16384 + n * 128 + k0) = L1;
        *(bf16x8*)(w1L + 1 * 16384 + n * 128 + k0) = L2;
        *(bf16x8*)(w1L + 2 * 16384 + n * 128 + k0) = L3;
    }
    if (tid < 512) {                        // 32 rows x 16 slots
        int n = tid >> 4, k0 = (tid & 15) << 3;
        float v[8];
        #pragma unroll
        for (int j = 0; j < 8; ++j) v[j] = w2g[n * 128 + k0 + j];
        bf16x8 L1, L2, L3; split3x8(v, L1, L2, L3);
        *(bf16x8*)(w2L + 0 * 4096 + n * 128 + k0) = L1;
        *(bf16x8*)(w2L + 1 * 4096 + n * 128 + k0) = L2;
        *(bf16x8*)(w2L + 2 * 4096 + n * 128 + k0) = L3;
    }
}

// ---------------- tap helpers ---------------------------------------------
__device__ __forceinline__ void tap_load(const float* __restrict__ xg, int b, int irow,
                                         int jbase, int j, float v[8])
{
    int tpx = j & 63, cls = j >> 6;
    const float* cbase = xg + (b * 32 + cls) * 16384;
    #pragma unroll
    for (int t = 0; t < 8; ++t) {
        int di = (int)((0x22211000u >> (4 * t)) & 0xFu) - 1;
        int dj = (int)((0x21020210u >> (4 * t)) & 0xFu) - 1;
        int row = irow + di;
        int cc  = jbase + tpx + dj;
        bool okb = ((unsigned)row < 128u) && ((unsigned)cc < 128u);
        int off = okb ? (row * 128 + cc) : 0;      // clamped: always-safe load
        float x = cbase[off];
        v[t] = okb ? x : 0.0f;
    }
}

__device__ __forceinline__ void tap_write(U16* sL, int j, const float v[8])
{
    int tpx = j & 63, cls = j >> 6;
    bf16x8 T1, T2, T3; split3x8(v, T1, T2, T3);
    int to = tpx * 136 + 32 + cls * 8;
    *(bf16x8*)&sL[to] = T1;
    *(bf16x8*)&sL[8704 + to] = T2;
    *(bf16x8*)&sL[17408 + to] = T3;
}

// ---------------- main ----------------------------------------------------
// B=64, C=32, H=W=128, PERC=112(pad->128), NHID=128, NCLS=10. fp32 in/out.
// block = 256 threads = 4 waves = 64 pixels (one b, one row, half width).
// LDS: 3 bf16 limb planes [64][136] (perc, then h); dxl f32 [64][37] aliases.
__global__ __launch_bounds__(256, 3)
void cann_kernel(const float* __restrict__ xg,  const U16* __restrict__ w1L,
                 const U16* __restrict__ w2L,
                 const float* __restrict__ b1g, const float* __restrict__ b2g,
                 const float* __restrict__ gg,  const float* __restrict__ bg,
                 float* __restrict__ outg)
{
    __shared__ __align__(16) U16 sL[3 * 8704];        // 52224 B -> 3 blocks/CU

    const int tid  = threadIdx.x;
    // XCD-contiguous swizzle: 16384 blocks, 8 XCDs, bijective (16384 % 8 == 0).
    // Consecutive swizzled ids (same b, adjacent rows) land on the same XCD ->
    // tap-row overlap is served by that XCD's L2.
    const int bid0 = blockIdx.x;
    const int bid  = (bid0 & 7) * 2048 + (bid0 >> 3);
    const int jseg = bid & 1;
    const int irow = (bid >> 1) & 127;
    const int b    = bid >> 8;
    const int jbase = jseg << 6;
    const int lane = tid & 63;
    const int wv   = tid >> 6;
    const int quad = lane >> 4;
    const int col  = lane & 15;

    // ---------------- Phase A: front-load ALL global reads --------------------
    const int px = tid & 63, cg = tid >> 6;
    const float* srcA = xg + (b * 32 + cg * 8) * 16384 + irow * 128 + jbase + px;
    float va[8];
    #pragma unroll
    for (int i = 0; i < 8; ++i) va[i] = srcA[i * 16384];   // coalesced across lanes

    float vt0[8], vt1[8], vt2[8];                          // 640 tap jobs
    tap_load(xg, b, irow, jbase, tid,       vt0);
    tap_load(xg, b, irow, jbase, tid + 256, vt1);
    if (tid < 128) tap_load(xg, b, irow, jbase, tid + 512, vt2);

    // residual x for this wave's stage-2 tile (L1/L2-hot: same lines as (a))
    float xs[2][4];
    #pragma unroll
    for (int n2 = 0; n2 < 2; ++n2)
        #pragma unroll
        for (int r = 0; r < 4; ++r)
            xs[n2][r] = xg[(b * 32 + n2 * 16 + col) * 16384 + irow * 128 + jbase
                           + wv * 16 + quad * 4 + r];

    const float b1v0 = b1g[wv * 32 + col];
    const float b1v1 = b1g[wv * 32 + 16 + col];
    const float b2v0 = b2g[col];
    const float b2v1 = b2g[16 + col];
    float g2v[2], be2v[2];
    g2v[0] = gg[col];      g2v[1] = gg[16 + col];
    be2v[0] = bg[col];     be2v[1] = bg[16 + col];

    // ---------------- splits + LDS writes (loads already in flight) -----------
    {
        bf16x8 L1, L2, L3; split3x8(va, L1, L2, L3);
        int o = px * 136 + cg * 8;
        *(bf16x8*)&sL[o] = L1;
        *(bf16x8*)&sL[8704 + o] = L2;
        *(bf16x8*)&sL[17408 + o] = L3;
    }
    tap_write(sL, tid,       vt0);
    tap_write(sL, tid + 256, vt1);
    if (tid < 128) tap_write(sL, tid + 512, vt2);
    if (tid < 128) {                                      // zero pad k=112..127
        int zo = (tid >> 1) * 136 + 112 + (tid & 1) * 8;
        uint4 z = make_uint4(0u, 0u, 0u, 0u);
        *(uint4*)&sL[zo] = z;
        *(uint4*)&sL[8704 + zo] = z;
        *(uint4*)&sL[17408 + zo] = z;
    }

    // prefetch stage-1 B fragments for ks=0 (independent of LDS -> hides
    // under the barrier wait). bw[buf][L*2+n2], buf = ks&1.
    const int n0r = wv * 32 + col;
    bf16x8 bw[2][6];
    #pragma unroll
    for (int L = 0; L < 3; ++L)
        #pragma unroll
        for (int n2 = 0; n2 < 2; ++n2)
            bw[0][L * 2 + n2] =
                *(const bf16x8*)(w1L + L * 16384 + (n0r + n2 * 16) * 128 + quad * 8);

    __syncthreads();   // B1: staging complete

    // ---------------- Stage 1: h = relu(perc @ w1^T + b1), split-N over waves --
    // ks-outer with 2-deep operand double-buffer: each w1 fragment loaded ONCE,
    // prefetched one ks-iteration (48 MFMAs) ahead of use.
    const f32x4 fz = {0.f, 0.f, 0.f, 0.f};
    f32x4 acc1[4][2];
    #pragma unroll
    for (int mt = 0; mt < 4; ++mt) { acc1[mt][0] = fz; acc1[mt][1] = fz; }

    #pragma unroll
    for (int ks = 0; ks < 4; ++ks) {
        if (ks < 3) {
            #pragma unroll
            for (int L = 0; L < 3; ++L)
                #pragma unroll
                for (int n2 = 0; n2 < 2; ++n2)
                    bw[(ks + 1) & 1][L * 2 + n2] =
                        *(const bf16x8*)(w1L + L * 16384 + (n0r + n2 * 16) * 128
                                         + (ks + 1) * 32 + quad * 8);
        }
        #pragma unroll
        for (int mt = 0; mt < 4; ++mt) {
            int ao = (mt * 16 + col) * 136 + ks * 32 + quad * 8;
            bf16x8 A1 = *(const bf16x8*)&sL[ao];
            bf16x8 A2 = *(const bf16x8*)&sL[8704 + ao];
            bf16x8 A3 = *(const bf16x8*)&sL[17408 + ao];
            #pragma unroll
            for (int n2 = 0; n2 < 2; ++n2) {
                // same per-accumulator order as before: ks ascending,
                // A1B1, A1B2, A2B1, A1B3, A2B2, A3B1  -> bit-identical sums
                f32x4 a = acc1[mt][n2];
                a = __builtin_amdgcn_mfma_f32_16x16x32_bf16(A1, bw[ks & 1][0 + n2], a, 0, 0, 0);
                a = __builtin_amdgcn_mfma_f32_16x16x32_bf16(A1, bw[ks & 1][2 + n2], a, 0, 0, 0);
                a = __builtin_amdgcn_mfma_f32_16x16x32_bf16(A2, bw[ks & 1][0 + n2], a, 0, 0, 0);
                a = __builtin_amdgcn_mfma_f32_16x16x32_bf16(A1, bw[ks & 1][4 + n2], a, 0, 0, 0);
                a = __builtin_amdgcn_mfma_f32_16x16x32_bf16(A2, bw[ks & 1][2 + n2], a, 0, 0, 0);
                a = __builtin_amdgcn_mfma_f32_16x16x32_bf16(A3, bw[ks & 1][0 + n2], a, 0, 0, 0);
                acc1[mt][n2] = a;
            }
        }
    }
    __syncthreads();   // B2: all perc reads done -> planes reusable for h

    // h -> 3 limb planes (exact split of relu(acc+b1))
    #pragma unroll
    for (int mt = 0; mt < 4; ++mt)
        #pragma unroll
        for (int n2 = 0; n2 < 2; ++n2) {
            float bb = n2 ? b1v1 : b1v0;
            #pragma unroll
            for (int r = 0; r < 4; ++r) {
                float v = fmaxf(acc1[mt][n2][r] + bb, 0.0f);
                U16 u1, u2, u3; split3(v, u1, u2, u3);
                int ho = (mt * 16 + quad * 4 + r) * 136 + wv * 32 + n2 * 16 + col;
                sL[ho] = u1; sL[8704 + ho] = u2; sL[17408 + ho] = u3;
            }
        }

    // prefetch stage-2 B fragments for ks=0 (independent of LDS)
    bf16x8 w2f[2][6];
    #pragma unroll
    for (int L = 0; L < 3; ++L)
        #pragma unroll
        for (int n2 = 0; n2 < 2; ++n2)
            w2f[0][L * 2 + n2] =
                *(const bf16x8*)(w2L + L * 4096 + (n2 * 16 + col) * 128 + quad * 8);

    __syncthreads();   // B3: h complete

    // ---------------- Stage 2: dx = h @ w2^T, waves split-M (16 pixels each) ---
    f32x4 acc2[2];
    acc2[0] = fz; acc2[1] = fz;
    #pragma unroll
    for (int ks = 0; ks < 4; ++ks) {
        if (ks < 3) {
            #pragma unroll
            for (int L = 0; L < 3; ++L)
                #pragma unroll
                for (int n2 = 0; n2 < 2; ++n2)
                    w2f[(ks + 1) & 1][L * 2 + n2] =
                        *(const bf16x8*)(w2L + L * 4096 + (n2 * 16 + col) * 128
                                         + (ks + 1) * 32 + quad * 8);
        }
        int ho = (wv * 16 + col) * 136 + ks * 32 + quad * 8;
        bf16x8 H1 = *(const bf16x8*)&sL[ho];
        bf16x8 H2 = *(const bf16x8*)&sL[8704 + ho];
        bf16x8 H3 = *(const bf16x8*)&sL[17408 + ho];
        #pragma unroll
        for (int n2 = 0; n2 < 2; ++n2) {
            f32x4 a = acc2[n2];
            a = __builtin_amdgcn_mfma_f32_16x16x32_bf16(H1, w2f[ks & 1][0 + n2], a, 0, 0, 0);
            a = __builtin_amdgcn_mfma_f32_16x16x32_bf16(H1, w2f[ks & 1][2 + n2], a, 0, 0, 0);
            a = __builtin_amdgcn_mfma_f32_16x16x32_bf16(H2, w2f[ks & 1][0 + n2], a, 0, 0, 0);
            a = __builtin_amdgcn_mfma_f32_16x16x32_bf16(H1, w2f[ks & 1][4 + n2], a, 0, 0, 0);
            a = __builtin_amdgcn_mfma_f32_16x16x32_bf16(H2, w2f[ks & 1][2 + n2], a, 0, 0, 0);
            a = __builtin_amdgcn_mfma_f32_16x16x32_bf16(H3, w2f[ks & 1][0 + n2], a, 0, 0, 0);
            acc2[n2] = a;
        }
    }

    // ---------------- Epilogue: in-register mask + LayerNorm (all 4 waves) -----
    // Lane (quad,col) holds pixel p = wv*16+quad*4+r, channels col and 16+col.
    // Channel reductions = 16-lane shfl_xor trees (max tree is exact, so the
    // keep decision is bit-identical to the sequential version).
    float fin[2][4];
    #pragma unroll
    for (int r = 0; r < 4; ++r) {
        float n0 = acc2[0][r] + b2v0 + xs[0][r];          // ch = col
        float n1 = acc2[1][r] + b2v1 + xs[1][r];          // ch = 16+col
        float cm = (col >= 1 && col <= 9) ? n0 : -3.0e38f;  // classes 1..9
        float z0 = (col == 0)             ? n0 : -3.0e38f;  // class 0
        #pragma unroll
        for (int m = 1; m < 16; m <<= 1) {
            cm = fmaxf(cm, __shfl_xor(cm, m, 64));
            z0 = fmaxf(z0, __shfl_xor(z0, m, 64));
        }
        float keep = (cm > z0) ? 1.0f : 0.0f;             // argmax != 0
        n0 = (col >= 10) ? n0 * keep : n0;                // hidden ch >= 10
        n1 = n1 * keep;                                   // ch 16..31 all hidden
        float s = n0 + n1;
        float q = n0 * n0 + n1 * n1;
        #pragma unroll
        for (int m = 1; m < 16; m <<= 1) {
            s += __shfl_xor(s, m, 64);
            q += __shfl_xor(q, m, 64);
        }
        float mu  = s * 0.03125f;
        float var = q * 0.03125f - mu * mu;
        float rstd = 1.0f / sqrtf(var + 1e-5f);
        fin[0][r] = (n0 - mu) * rstd * g2v[0] + be2v[0];
        fin[1][r] = (n1 - mu) * rstd * g2v[1] + be2v[1];
    }

    __syncthreads();   // B4a: all stage-2 LDS reads done -> plane mem reusable

    // transpose via LDS (stride 37: conflict-light writes, conflict-free reads)
    float* dxl = (float*)sL;
    #pragma unroll
    for (int n2 = 0; n2 < 2; ++n2)
        #pragma unroll
        for (int r = 0; r < 4; ++r) {
            int p = wv * 16 + quad * 4 + r;
            dxl[p * 37 + n2 * 16 + col] = fin[n2][r];
        }
    __syncthreads();   // B4: transposed values ready

    // fully parallel coalesced store: 256 threads x 8 values
    {
        int p  = tid & 63;
        int c0 = (tid >> 6) * 8;
        int base = b * 524288 + irow * 128 + jbase + p;
        #pragma unroll
        for (int i = 0; i < 8; ++i)
            outg[base + (c0 + i) * 16384] = dxl[p * 37 + c0 + i];   // coalesced
    }
}

extern "C" void kernel_launch(void* const* d_in, const int* in_sizes, int n_in,
                              void* d_out, int out_size, void* d_ws, size_t ws_size,
                              hipStream_t stream) {
    const float* x  = (const float*)d_in[0];
    const float* w1 = (const float*)d_in[1];
    const float* b1 = (const float*)d_in[2];
    const float* w2 = (const float*)d_in[3];
    const float* b2 = (const float*)d_in[4];
    const float* g  = (const float*)d_in[5];
    const float* be = (const float*)d_in[6];
    float* out = (float*)d_out;

    U16* w1L = (U16*)d_ws;                       // 98304 B
    U16* w2L = (U16*)((char*)d_ws + 98304);      // 24576 B (total 122880 <= ws)

    hipLaunchKernelGGL(prep_kernel, dim3(8), dim3(256), 0, stream, w1, w2, w1L, w2L);
    // grid: 64 (B) * 128 (rows) * 2 (W/64) = 16384 blocks
    hipLaunchKernelGGL(cann_kernel, dim3(16384), dim3(256), 0, stream,
                       x, w1L, w2L, b1, b2, g, be, out);
}